// Round 9
// baseline (216.480 us; speedup 1.0000x reference)
//
#include <hip/hip_runtime.h>
#include <hip/hip_bf16.h>

typedef __bf16 bf16_t;
typedef __bf16 bf16x4 __attribute__((ext_vector_type(4)));
typedef __bf16 bf16x8 __attribute__((ext_vector_type(8)));
typedef float f32x4 __attribute__((ext_vector_type(4)));
typedef float f32x16 __attribute__((ext_vector_type(16)));

// Problem constants: B=2, C=128, H=W=64 -> S=4096, NTOK=8192, NH=4, HC=32

// ---------------- workspace layout (bytes) ----------------
static constexpr size_t WS_WPK = 0;                       // 655,360
static constexpr size_t WS_PP  = 655360;                  // 3 x 2,097,152 (qp,kp,vp)
static constexpr size_t WS_VT  = WS_PP + 3ull*2097152;    // 2,097,152

// ---------------- kernel 1: weight transpose+cast via LDS tiles ----------------
struct WPtrs { const float* w1[5]; const float* w2[5]; };

__global__ __launch_bounds__(256) void prep_weights(WPtrs wp, bf16_t* __restrict__ dst) {
    __shared__ float ts[64][65];
    int bx = blockIdx.x;              // 80 blocks: 5 pairs x (8 w1-tiles + 8 w2-tiles)
    int p = bx >> 4;
    int t = bx & 15;
    const float* src; int sld, dld, r0, c0; bf16_t* d;
    if (t < 8) {  // w1 [128][256] -> w1T [256][128]
        src = wp.w1[p]; sld = 256; dld = 128;
        r0 = (t >> 2) * 64; c0 = (t & 3) * 64;
        d = dst + p * 65536;
    } else {      // w2 [256][128] -> w2T [128][256]
        int tt = t - 8;
        src = wp.w2[p]; sld = 128; dld = 256;
        r0 = (tt >> 1) * 64; c0 = (tt & 1) * 64;
        d = dst + p * 65536 + 32768;
    }
    for (int i = threadIdx.x; i < 4096; i += 256) {
        int r = i >> 6, c = i & 63;
        ts[r][c] = src[(r0 + r) * sld + c0 + c];
    }
    __syncthreads();
    for (int i = threadIdx.x; i < 4096; i += 256) {
        int c = i >> 6, r = i & 63;
        d[(c0 + c) * dld + (r0 + r)] = (bf16_t)ts[r][c];
    }
}

// ---------------- kernel 2: fused transpose+LayerNorm+MLP-pair projection ----------------
struct ProjArgs {
    const float* src[3]; const float* g[3]; const float* bb[3];
    const float* B1[3]; const float* B2[3];
    bf16_t* OUT[3]; bf16_t* VTOUT;
};

__global__ __launch_bounds__(256) void projln_kernel(ProjArgs a, const bf16_t* __restrict__ wpk) {
    __shared__ float xs[16][132];
    __shared__ bf16_t al[16][136];
    __shared__ bf16_t hl[16][264];
    int z = blockIdx.y;
    int m0 = blockIdx.x * 16;
    int b = m0 >> 12, s0 = m0 & 4095;
    int tx = threadIdx.x;
    int w = tx >> 6;
    int lane = tx & 63;
    int quad = lane >> 4;
    int l15 = lane & 15;

    const float* src = a.src[z];
    for (int idx = tx; idx < 2048; idx += 256) {
        int c = idx >> 4, tt = idx & 15;
        xs[tt][c] = src[(b * 128 + c) * 4096 + s0 + tt];
    }
    __syncthreads();

    {
        int t = tx >> 4, j = tx & 15;
        float sum = 0.f, sq = 0.f;
#pragma unroll
        for (int k = 0; k < 8; ++k) { float v = xs[t][j + 16 * k]; sum += v; sq += v * v; }
        sum += __shfl_xor(sum, 1); sq += __shfl_xor(sq, 1);
        sum += __shfl_xor(sum, 2); sq += __shfl_xor(sq, 2);
        sum += __shfl_xor(sum, 4); sq += __shfl_xor(sq, 4);
        sum += __shfl_xor(sum, 8); sq += __shfl_xor(sq, 8);
        float mu = sum * (1.0f / 128.0f);
        float var = sq * (1.0f / 128.0f) - mu * mu;
        float rs = rsqrtf(var + 1e-5f);
        const float* g = a.g[z];
        const float* bb = a.bb[z];
#pragma unroll
        for (int k = 0; k < 8; ++k) {
            int c = j + 16 * k;
            al[t][c] = (bf16_t)((xs[t][c] - mu) * rs * g[c] + bb[c]);
        }
    }
    __syncthreads();

    const bf16_t* w1t = wpk + (size_t)z * 65536;
    const bf16_t* w2t = w1t + 32768;
    bf16x8 af[4];
#pragma unroll
    for (int kt = 0; kt < 4; ++kt) af[kt] = *(const bf16x8*)(&al[l15][kt * 32 + quad * 8]);

#pragma unroll
    for (int sub = 0; sub < 4; ++sub) {
        int n = w * 64 + sub * 16 + l15;
        const bf16_t* wrow = w1t + (size_t)n * 128 + quad * 8;
        f32x4 acc = {0.f, 0.f, 0.f, 0.f};
#pragma unroll
        for (int kt = 0; kt < 4; ++kt) {
            bf16x8 bfrag = *(const bf16x8*)(wrow + kt * 32);
            acc = __builtin_amdgcn_mfma_f32_16x16x32_bf16(af[kt], bfrag, acc, 0, 0, 0);
        }
        float bn = a.B1[z][n];
#pragma unroll
        for (int r = 0; r < 4; ++r) {
            float v = acc[r] + bn;
            v = v > 0.f ? v : 0.01f * v;
            hl[quad * 4 + r][n] = (bf16_t)v;
        }
    }
    __syncthreads();

    bf16x8 hf[8];
#pragma unroll
    for (int kt = 0; kt < 8; ++kt)
        hf[kt] = *(const bf16x8*)(&hl[l15][kt * 32 + quad * 8]);

#pragma unroll
    for (int sub = 0; sub < 2; ++sub) {
        int n = w * 32 + sub * 16 + l15;
        const bf16_t* wrow = w2t + (size_t)n * 256 + quad * 8;
        f32x4 acc = {0.f, 0.f, 0.f, 0.f};
#pragma unroll
        for (int kt = 0; kt < 8; ++kt) {
            bf16x8 bfrag = *(const bf16x8*)(wrow + kt * 32);
            acc = __builtin_amdgcn_mfma_f32_16x16x32_bf16(hf[kt], bfrag, acc, 0, 0, 0);
        }
        float bn = a.B2[z][n];
        float vals[4];
#pragma unroll
        for (int r = 0; r < 4; ++r) vals[r] = acc[r] + bn;
#pragma unroll
        for (int r = 0; r < 4; ++r)
            a.OUT[z][(size_t)(m0 + quad * 4 + r) * 128 + n] = (bf16_t)vals[r];
        if (z == 2) {
            int bh = b * 4 + (n >> 5), d = n & 31;
            bf16x4 tv = {(bf16_t)vals[0], (bf16_t)vals[1], (bf16_t)vals[2], (bf16_t)vals[3]};
            *(bf16x4*)(a.VTOUT + ((size_t)(bh * 32 + d)) * 4096 + s0 + quad * 4) = tv;
        }
    }
}

// ---------------- kernel 3: fused attention + in-LDS combine + mlp1 + mlp2 + output ----------------
// Block = 32 tokens, 512 threads (8 waves). Wave (h, half): head h, keys half*2048..+2048,
// pipelined no-max exp2 softmax (r8 loop, single 32-query subtile), l-sum via all-ones MFMA.
// Unnormalized O^T partials + l go to LDS; combine -> x tile; then mlp1(+vp res, in LDS)
// -> mlp2(+rs1 res) -> fp32 transposed store. Zero global round-trips after attention.
__global__ __launch_bounds__(512, 2) void attn_mlp_kernel(const bf16_t* __restrict__ qp,
                                                          const bf16_t* __restrict__ kp,
                                                          const bf16_t* __restrict__ vt,
                                                          const bf16_t* __restrict__ vp,
                                                          const bf16_t* __restrict__ wpk,
                                                          const float* __restrict__ b1a,
                                                          const float* __restrict__ b2a,
                                                          const float* __restrict__ b1b,
                                                          const float* __restrict__ b2b,
                                                          float* __restrict__ out) {
    __shared__ bf16_t opl[2][32][136];   // unnormalized O^T partials per half
    __shared__ float ll[2][4][32];       // l partials per half/head/query
    __shared__ bf16_t xl[32][136];       // combined attention out (mlp1 A-tile)
    __shared__ bf16_t al2[32][136];      // rs1
    __shared__ bf16_t hl[32][264];       // hidden (256) tile

    int tx = threadIdx.x;
    int wid = tx >> 6;                  // 0..7
    int h = wid & 3;
    int half = wid >> 2;
    int lane = tx & 63;
    int l31 = lane & 31;
    int h5 = lane >> 5;
    int quad = lane >> 4;               // valid within wave for mlp (uses l15)
    int l15 = lane & 15;
    int wq = lane >> 4;                 // nothing
    (void)wq;

    int t0 = blockIdx.x * 32;
    int b = t0 >> 12;
    int s0 = t0 & 4095;
    int bh = b * 4 + h;

    constexpr float kScale = 0.17677669529663687f * 1.4426950408889634f; // 1/sqrt(32)*log2(e)

    // ---- Q frags (32 queries = block tokens), pre-scaled ----
    const bf16_t* qrow = qp + ((size_t)(b * 4096 + s0 + l31)) * 128 + h * 32 + h5 * 8;
    bf16x8 q0r = *(const bf16x8*)(qrow);
    bf16x8 q1r = *(const bf16x8*)(qrow + 16);
    bf16x8 qf0, qf1;
#pragma unroll
    for (int j = 0; j < 8; ++j) {
        qf0[j] = (bf16_t)((float)q0r[j] * kScale);
        qf1[j] = (bf16_t)((float)q1r[j] * kScale);
    }

    bf16x8 a_ones;
#pragma unroll
    for (int j = 0; j < 8; ++j) a_ones[j] = (bf16_t)1.0f;

    int key_m = (l31 & ~12) | ((l31 & 4) << 1) | ((l31 & 8) >> 1);
    const bf16_t* kb = kp + ((size_t)(b * 4096) + half * 2048 + key_m) * 128 + h * 32 + h5 * 8;
    const bf16_t* vb = vt + ((size_t)(bh * 32) + l31) * 4096 + half * 2048 + h5 * 8;

    f32x16 acca = {0.f,0.f,0.f,0.f,0.f,0.f,0.f,0.f,0.f,0.f,0.f,0.f,0.f,0.f,0.f,0.f};
    f32x16 lacc = acca;
    f32x16 zero16 = acca;

    // ---- prologue ----
    bf16x8 kcur0 = *(const bf16x8*)(kb);
    bf16x8 kcur1 = *(const bf16x8*)(kb + 16);
    bf16x8 vuse0 = *(const bf16x8*)(vb);
    bf16x8 vuse1 = *(const bf16x8*)(vb + 16);

    f32x16 sca = __builtin_amdgcn_mfma_f32_32x32x16_bf16(kcur0, qf0, zero16, 0, 0, 0);
    sca = __builtin_amdgcn_mfma_f32_32x32x16_bf16(kcur1, qf1, sca, 0, 0, 0);

    bf16x8 kfB0 = *(const bf16x8*)(kb + 4096);
    bf16x8 kfB1 = *(const bf16x8*)(kb + 4096 + 16);
    bf16x8 vfB0 = *(const bf16x8*)(vb + 32);
    bf16x8 vfB1 = *(const bf16x8*)(vb + 32 + 16);

    for (int it = 1; it < 64; ++it) {
        int nt = (it < 63) ? it + 1 : 63;
        bf16x8 nk0 = *(const bf16x8*)(kb + (size_t)nt * 4096);
        bf16x8 nk1 = *(const bf16x8*)(kb + (size_t)nt * 4096 + 16);
        bf16x8 nv0 = *(const bf16x8*)(vb + nt * 32);
        bf16x8 nv1 = *(const bf16x8*)(vb + nt * 32 + 16);

        bf16x8 pf0, pf1;
#pragma unroll
        for (int j = 0; j < 8; ++j) {
            pf0[j] = (bf16_t)__builtin_amdgcn_exp2f(sca[j]);
            pf1[j] = (bf16_t)__builtin_amdgcn_exp2f(sca[8 + j]);
        }
        lacc = __builtin_amdgcn_mfma_f32_32x32x16_bf16(a_ones, pf0, lacc, 0, 0, 0);
        lacc = __builtin_amdgcn_mfma_f32_32x32x16_bf16(a_ones, pf1, lacc, 0, 0, 0);
        acca = __builtin_amdgcn_mfma_f32_32x32x16_bf16(vuse0, pf0, acca, 0, 0, 0);
        acca = __builtin_amdgcn_mfma_f32_32x32x16_bf16(vuse1, pf1, acca, 0, 0, 0);

        sca = __builtin_amdgcn_mfma_f32_32x32x16_bf16(kfB0, qf0, zero16, 0, 0, 0);
        sca = __builtin_amdgcn_mfma_f32_32x32x16_bf16(kfB1, qf1, sca, 0, 0, 0);

        vuse0 = vfB0; vuse1 = vfB1;
        kfB0 = nk0; kfB1 = nk1; vfB0 = nv0; vfB1 = nv1;
    }
    {   // epilogue tile 63
        bf16x8 pf0, pf1;
#pragma unroll
        for (int j = 0; j < 8; ++j) {
            pf0[j] = (bf16_t)__builtin_amdgcn_exp2f(sca[j]);
            pf1[j] = (bf16_t)__builtin_amdgcn_exp2f(sca[8 + j]);
        }
        lacc = __builtin_amdgcn_mfma_f32_32x32x16_bf16(a_ones, pf0, lacc, 0, 0, 0);
        lacc = __builtin_amdgcn_mfma_f32_32x32x16_bf16(a_ones, pf1, lacc, 0, 0, 0);
        acca = __builtin_amdgcn_mfma_f32_32x32x16_bf16(vuse0, pf0, acca, 0, 0, 0);
        acca = __builtin_amdgcn_mfma_f32_32x32x16_bf16(vuse1, pf1, acca, 0, 0, 0);
    }

    // ---- stash O^T partial + l in LDS ----
#pragma unroll
    for (int g = 0; g < 4; ++g) {
        bf16x4 ov = {(bf16_t)acca[4*g], (bf16_t)acca[4*g+1], (bf16_t)acca[4*g+2], (bf16_t)acca[4*g+3]};
        *(bf16x4*)(&opl[half][l31][h * 32 + 8 * g + 4 * h5]) = ov;
    }
    if (h5 == 0) ll[half][h][l31] = lacc[0];   // all lacc rows equal the colsum
    __syncthreads();

    // ---- combine halves + normalize -> x tile ----
    {
        int t = tx >> 4;               // token 0..31
        int cg = tx & 15;              // channel octet
        int hh = cg >> 2;
        float invl = 1.0f / (ll[0][hh][t] + ll[1][hh][t]);
        bf16x8 o0 = *(const bf16x8*)(&opl[0][t][cg * 8]);
        bf16x8 o1 = *(const bf16x8*)(&opl[1][t][cg * 8]);
        bf16x8 x8;
#pragma unroll
        for (int j = 0; j < 8; ++j) x8[j] = (bf16_t)(((float)o0[j] + (float)o1[j]) * invl);
        *(bf16x8*)(&xl[t][cg * 8]) = x8;
    }
    __syncthreads();

    const bf16_t* w1ta = wpk + 3ull * 65536;
    const bf16_t* w2ta = w1ta + 32768;
    const bf16_t* w1tb = wpk + 4ull * 65536;
    const bf16_t* w2tb = w1tb + 32768;
    int w8 = wid;                       // 0..7: n-slice owner

    // ---- mlp1 phase 1: h = LReLU(x @ W1a^T + b1a) ----
    {
        bf16x8 af[2][4];
#pragma unroll
        for (int mt = 0; mt < 2; ++mt)
#pragma unroll
            for (int kt = 0; kt < 4; ++kt)
                af[mt][kt] = *(const bf16x8*)(&xl[mt * 16 + l15][kt * 32 + quad * 8]);
#pragma unroll
        for (int sub = 0; sub < 2; ++sub) {
            int n = w8 * 32 + sub * 16 + l15;
            const bf16_t* wrow = w1ta + (size_t)n * 128 + quad * 8;
            f32x4 acc[2] = {{0.f,0.f,0.f,0.f},{0.f,0.f,0.f,0.f}};
#pragma unroll
            for (int kt = 0; kt < 4; ++kt) {
                bf16x8 bfrag = *(const bf16x8*)(wrow + kt * 32);
                acc[0] = __builtin_amdgcn_mfma_f32_16x16x32_bf16(af[0][kt], bfrag, acc[0], 0, 0, 0);
                acc[1] = __builtin_amdgcn_mfma_f32_16x16x32_bf16(af[1][kt], bfrag, acc[1], 0, 0, 0);
            }
            float bn = b1a[n];
#pragma unroll
            for (int mt = 0; mt < 2; ++mt)
#pragma unroll
                for (int r = 0; r < 4; ++r) {
                    float v = acc[mt][r] + bn;
                    v = v > 0.f ? v : 0.01f * v;
                    hl[mt * 16 + quad * 4 + r][n] = (bf16_t)v;
                }
        }
    }
    __syncthreads();

    // ---- mlp1 phase 2 (+vp residual) -> rs1 in LDS ----
    {
        bf16x8 hf[2][8];
#pragma unroll
        for (int mt = 0; mt < 2; ++mt)
#pragma unroll
            for (int kt = 0; kt < 8; ++kt)
                hf[mt][kt] = *(const bf16x8*)(&hl[mt * 16 + l15][kt * 32 + quad * 8]);
        int n = w8 * 16 + l15;
        const bf16_t* wrow = w2ta + (size_t)n * 256 + quad * 8;
        f32x4 acc[2] = {{0.f,0.f,0.f,0.f},{0.f,0.f,0.f,0.f}};
#pragma unroll
        for (int kt = 0; kt < 8; ++kt) {
            bf16x8 bfrag = *(const bf16x8*)(wrow + kt * 32);
            acc[0] = __builtin_amdgcn_mfma_f32_16x16x32_bf16(hf[0][kt], bfrag, acc[0], 0, 0, 0);
            acc[1] = __builtin_amdgcn_mfma_f32_16x16x32_bf16(hf[1][kt], bfrag, acc[1], 0, 0, 0);
        }
        float bn = b2a[n];
#pragma unroll
        for (int mt = 0; mt < 2; ++mt)
#pragma unroll
            for (int r = 0; r < 4; ++r) {
                int m = t0 + mt * 16 + quad * 4 + r;
                float v = acc[mt][r] + bn + (float)vp[(size_t)m * 128 + n];
                al2[mt * 16 + quad * 4 + r][n] = (bf16_t)v;
            }
    }
    __syncthreads();

    // ---- mlp2 phase 1 ----
    {
        bf16x8 af[2][4];
#pragma unroll
        for (int mt = 0; mt < 2; ++mt)
#pragma unroll
            for (int kt = 0; kt < 4; ++kt)
                af[mt][kt] = *(const bf16x8*)(&al2[mt * 16 + l15][kt * 32 + quad * 8]);
#pragma unroll
        for (int sub = 0; sub < 2; ++sub) {
            int n = w8 * 32 + sub * 16 + l15;
            const bf16_t* wrow = w1tb + (size_t)n * 128 + quad * 8;
            f32x4 acc[2] = {{0.f,0.f,0.f,0.f},{0.f,0.f,0.f,0.f}};
#pragma unroll
            for (int kt = 0; kt < 4; ++kt) {
                bf16x8 bfrag = *(const bf16x8*)(wrow + kt * 32);
                acc[0] = __builtin_amdgcn_mfma_f32_16x16x32_bf16(af[0][kt], bfrag, acc[0], 0, 0, 0);
                acc[1] = __builtin_amdgcn_mfma_f32_16x16x32_bf16(af[1][kt], bfrag, acc[1], 0, 0, 0);
            }
            float bn = b1b[n];
#pragma unroll
            for (int mt = 0; mt < 2; ++mt)
#pragma unroll
                for (int r = 0; r < 4; ++r) {
                    float v = acc[mt][r] + bn;
                    v = v > 0.f ? v : 0.01f * v;
                    hl[mt * 16 + quad * 4 + r][n] = (bf16_t)v;
                }
        }
    }
    __syncthreads();

    // ---- mlp2 phase 2 (+rs1 residual) -> fp32 transposed output ----
    {
        bf16x8 hf[2][8];
#pragma unroll
        for (int mt = 0; mt < 2; ++mt)
#pragma unroll
            for (int kt = 0; kt < 8; ++kt)
                hf[mt][kt] = *(const bf16x8*)(&hl[mt * 16 + l15][kt * 32 + quad * 8]);
        int n = w8 * 16 + l15;
        const bf16_t* wrow = w2tb + (size_t)n * 256 + quad * 8;
        f32x4 acc[2] = {{0.f,0.f,0.f,0.f},{0.f,0.f,0.f,0.f}};
#pragma unroll
        for (int kt = 0; kt < 8; ++kt) {
            bf16x8 bfrag = *(const bf16x8*)(wrow + kt * 32);
            acc[0] = __builtin_amdgcn_mfma_f32_16x16x32_bf16(hf[0][kt], bfrag, acc[0], 0, 0, 0);
            acc[1] = __builtin_amdgcn_mfma_f32_16x16x32_bf16(hf[1][kt], bfrag, acc[1], 0, 0, 0);
        }
        float bn = b2b[n];
#pragma unroll
        for (int mt = 0; mt < 2; ++mt) {
            f32x4 ov;
#pragma unroll
            for (int r = 0; r < 4; ++r)
                ov[r] = acc[mt][r] + bn + (float)al2[mt * 16 + quad * 4 + r][n];
            *(f32x4*)(out + ((size_t)(b * 128 + n)) * 4096 + s0 + mt * 16 + quad * 4) = ov;
        }
    }
}

// ---------------- launch ----------------
extern "C" void kernel_launch(void* const* d_in, const int* in_sizes, int n_in,
                              void* d_out, int out_size, void* d_ws, size_t ws_size,
                              hipStream_t stream) {
    const float* q = (const float*)d_in[0];
    const float* k = (const float*)d_in[1];
    const float* v = (const float*)d_in[2];
    const float* ln_g[3] = {(const float*)d_in[3], (const float*)d_in[9], (const float*)d_in[15]};
    const float* ln_b[3] = {(const float*)d_in[4], (const float*)d_in[10], (const float*)d_in[16]};
    const float* w1[5] = {(const float*)d_in[5], (const float*)d_in[11], (const float*)d_in[17],
                          (const float*)d_in[21], (const float*)d_in[25]};
    const float* b1[5] = {(const float*)d_in[6], (const float*)d_in[12], (const float*)d_in[18],
                          (const float*)d_in[22], (const float*)d_in[26]};
    const float* w2[5] = {(const float*)d_in[7], (const float*)d_in[13], (const float*)d_in[19],
                          (const float*)d_in[23], (const float*)d_in[27]};
    const float* b2[5] = {(const float*)d_in[8], (const float*)d_in[14], (const float*)d_in[20],
                          (const float*)d_in[24], (const float*)d_in[28]};
    float* out = (float*)d_out;

    char* ws = (char*)d_ws;
    bf16_t* wpk = (bf16_t*)(ws + WS_WPK);
    bf16_t* pp  = (bf16_t*)(ws + WS_PP);
    bf16_t* vtb = (bf16_t*)(ws + WS_VT);

    // 1. weight pack
    WPtrs wp;
    for (int p = 0; p < 5; ++p) { wp.w1[p] = w1[p]; wp.w2[p] = w2[p]; }
    prep_weights<<<80, 256, 0, stream>>>(wp, wpk);

    // 2. fused LN + projections; v emits vT
    ProjArgs pa;
    pa.src[0] = q; pa.src[1] = k; pa.src[2] = v;
    for (int i = 0; i < 3; ++i) {
        pa.g[i] = ln_g[i]; pa.bb[i] = ln_b[i];
        pa.B1[i] = b1[i]; pa.B2[i] = b2[i];
        pa.OUT[i] = pp + (size_t)i * 1048576;
    }
    pa.VTOUT = vtb;
    projln_kernel<<<dim3(512, 3), 256, 0, stream>>>(pa, wpk);

    // 3. fused attention + combine + mlp1 + mlp2 + output
    attn_mlp_kernel<<<256, 512, 0, stream>>>(pp, pp + 1048576, vtb,
                                             pp + 2ull * 1048576, wpk,
                                             b1[3], b2[3], b1[4], b2[4], out);
}